// Round 6
// baseline (1536.035 us; speedup 1.0000x reference)
//
#include <hip/hip_runtime.h>
#include <hip/hip_bf16.h>
#include <math.h>

// ---------- problem constants ----------
#define BB 4
#define LL 1024
#define DD 512
#define DI 1024
#define NST 16

typedef unsigned short ushort_t;
typedef __attribute__((ext_vector_type(8))) short short8;
typedef __attribute__((ext_vector_type(4))) float f32x4;
typedef __attribute__((ext_vector_type(4))) unsigned short ushort4_t;

__device__ __forceinline__ float silu_f(float x) { return x / (1.f + __expf(-x)); }

__device__ __forceinline__ ushort_t f2bf(float f) {
  union { float f; unsigned u; } v; v.f = f;
  unsigned r = v.u + 0x7fffu + ((v.u >> 16) & 1u);
  return (ushort_t)(r >> 16);
}
__device__ __forceinline__ float bf2f(ushort_t h) {
  union { unsigned u; float f; } v; v.u = ((unsigned)h) << 16;
  return v.f;
}

__device__ __forceinline__ void gl_lds16(const ushort_t* src, ushort_t* dst) {
  __builtin_amdgcn_global_load_lds(
      (const __attribute__((address_space(1))) void*)src,
      (__attribute__((address_space(3))) void*)dst, 16, 0, 0);
}

// ======================= bf16 MFMA GEMM (2-phase double-buffered) =======================
// C[m,n] = op( sum_k A[m,k]*Bt[n,k] + bias );  A: M x K bf16, Bt: N x K bf16
// BM=128, BK=64, 4 waves. BN=128: wave grid 2x2 (64x64/wave). BN=64: 4x1 (32x64).
// ACT: 0 none 1 silu 2 gelu 3 softplus ; BIASM: 0 none 1 col 2 row
// CMODE: 0 store, 1 += (f32) ; FLIPA/FLIPC: row ^ 1023 ; OUTBF: C bf16
// SPLITK: blockIdx.z = k-split; A/B advance zz*K, C advances zz*sC (partials)
template <int BN, int ACT, int BIASM, int CMODE, int FLIPA, int FLIPC, int OUTBF, int SPLITK>
__global__ __launch_bounds__(256) void mgemm(
    const ushort_t* __restrict__ A, const ushort_t* __restrict__ Bt,
    const float* __restrict__ bias, void* __restrict__ Cv,
    int K, int lda, int ldb, int ldc, int nreal,
    long sA, long sB, long sC, float scale) {
  constexpr int MREP = (BN == 128) ? 4 : 2;
  constexpr int WM = MREP * 16;
  constexpr int NB = BN / 32;
  __shared__ ushort_t As[2][128 * 64];
  __shared__ ushort_t Bs[2][BN * 64];
  const int zz = blockIdx.z;
  const ushort_t* Ab = A + (SPLITK ? (long)zz * K : zz * sA);
  const ushort_t* Bb = Bt + (SPLITK ? (long)zz * K : zz * sB);
  const int flat = blockIdx.y * gridDim.x + blockIdx.x;
  const int nwg = gridDim.x * gridDim.y;
  const int id2 = (flat & 7) * (nwg >> 3) + (flat >> 3);
  const int bm = (id2 / gridDim.x) * 128;
  const int bn = (id2 % gridDim.x) * BN;
  const int tid = threadIdx.x;
  const int wave = tid >> 6, lane = tid & 63;
  const int rlo = lane & 15, q = lane >> 4;
  const int wr = (BN == 128) ? (wave >> 1) : wave;
  const int wc = (BN == 128) ? (wave & 1) : 0;

  f32x4 zero4 = {0.f, 0.f, 0.f, 0.f};
  f32x4 acc[MREP][4];
#pragma unroll
  for (int m = 0; m < MREP; ++m)
#pragma unroll
    for (int n = 0; n < 4; ++n) acc[m][n] = zero4;

  const int srow_off = lane >> 3;
  const int sslot = lane & 7;

#define STAGE_T(bb, k0)                                          \
  do {                                                           \
    _Pragma("unroll") for (int it = 0; it < 4; ++it) {           \
      int c = wave * 4 + it;                                     \
      int row = c * 8 + srow_off;                                \
      int gcol = ((sslot ^ (row & 7)) << 3);                     \
      int gra = bm + row;                                        \
      if (FLIPA) gra ^= 1023;                                    \
      gl_lds16(Ab + (long)gra * lda + (k0) + gcol, &As[bb][c * 512]); } \
    _Pragma("unroll") for (int it = 0; it < NB; ++it) {          \
      int c = wave * NB + it;                                    \
      int row = c * 8 + srow_off;                                \
      int gcol = ((sslot ^ (row & 7)) << 3);                     \
      gl_lds16(Bb + (long)(bn + row) * ldb + (k0) + gcol, &Bs[bb][c * 512]); } \
  } while (0)

  const int nt = K >> 6;
  STAGE_T(0, 0);
  __syncthreads();
  int cur = 0;
  for (int t = 0; t < nt; ++t) {
    if (t + 1 < nt) STAGE_T(cur ^ 1, (t + 1) * 64);
#pragma unroll
    for (int ks = 0; ks < 2; ++ks) {
      short8 af[MREP], bf[4];
#pragma unroll
      for (int m = 0; m < MREP; ++m) {
        int row = wr * WM + m * 16 + rlo;
        int ch = (ks * 4 + q) ^ (row & 7);
        af[m] = *(const short8*)&As[cur][row * 64 + ch * 8];
      }
#pragma unroll
      for (int n = 0; n < 4; ++n) {
        int row = wc * 64 + n * 16 + rlo;
        int ch = (ks * 4 + q) ^ (row & 7);
        bf[n] = *(const short8*)&Bs[cur][row * 64 + ch * 8];
      }
#pragma unroll
      for (int m = 0; m < MREP; ++m)
#pragma unroll
        for (int n = 0; n < 4; ++n)
          acc[m][n] = __builtin_amdgcn_mfma_f32_16x16x32_bf16(af[m], bf[n], acc[m][n], 0, 0, 0);
    }
    __syncthreads();
    cur ^= 1;
  }
#undef STAGE_T

#pragma unroll
  for (int m = 0; m < MREP; ++m) {
#pragma unroll
    for (int n = 0; n < 4; ++n) {
      int col = bn + wc * 64 + n * 16 + rlo;
      bool cok = (col < nreal);
#pragma unroll
      for (int j = 0; j < 4; ++j) {
        int row = bm + wr * WM + m * 16 + q * 4 + j;
        int orow = FLIPC ? (row ^ 1023) : row;
        float v = acc[m][n][j];
        if (!SPLITK || zz == 0) {
          if (BIASM == 1) v += bias[col];
          else if (BIASM == 2) v += bias[row];
        }
        if (ACT == 1) v = silu_f(v);
        else if (ACT == 2) v = 0.5f * v * (1.f + erff(v * 0.70710678118654752f));
        else if (ACT == 3) v = (v > 20.f) ? v : log1pf(__expf(v));
        if (cok) {
          if (OUTBF) {
            ushort_t* C = (ushort_t*)Cv + (long)zz * sC;
            C[(long)orow * ldc + col] = f2bf(scale * v);
          } else {
            float* C = (float*)Cv + (long)zz * sC;
            if (CMODE == 1) C[(long)orow * ldc + col] += scale * v;
            else C[(long)orow * ldc + col] = scale * v;
          }
        }
      }
    }
  }
}

// ======================= fused f32 -> bf16 weight conversion =======================
#define NSEG 10
struct CvtArgs {
  const float* src[NSEG];
  ushort_t* dst[NSEG];
  int start4[NSEG];
};
__global__ __launch_bounds__(256) void cvt_all_kernel(CvtArgs a, int total4) {
  int i = blockIdx.x * 256 + threadIdx.x;
  int stride = gridDim.x * 256;
  for (; i < total4; i += stride) {
    int seg = 0;
#pragma unroll
    for (int s = 1; s < NSEG; ++s)
      if (i >= a.start4[s]) seg = s;
    int off = i - a.start4[seg];
    float4 v = ((const float4*)a.src[seg])[off];
    ushort4_t o;
    o.x = f2bf(v.x); o.y = f2bf(v.y); o.z = f2bf(v.z); o.w = f2bf(v.w);
    *(ushort4_t*)(a.dst[seg] + (long)off * 4) = o;
  }
}

// dt_w (4 x 1024 x 32) f32 -> padded bf16 (4 x 1024 x 64), cols >=32 zero
__global__ __launch_bounds__(256) void cvtpad_dtw_kernel(const float* __restrict__ in,
                                                         ushort_t* __restrict__ out) {
  int i = blockIdx.x * 256 + threadIdx.x;  // 262144
  int k = i & 63;
  int dm = i >> 6;
  out[i] = (k < 32) ? f2bf(in[dm * 32 + k]) : (ushort_t)0;
}

// plain cvt (x -> bf16, locals phase)
__global__ __launch_bounds__(256) void cvt_kernel(const float* __restrict__ in,
                                                  ushort_t* __restrict__ out, long n) {
  long i = (long)blockIdx.x * 256 + threadIdx.x;
  long stride = (long)gridDim.x * 256;
  for (; i < n; i += stride) out[i] = f2bf(in[i]);
}

// ======================= reduce 4 split-K partials -> bf16 =======================
__global__ __launch_bounds__(256) void reduce4bf_kernel(const float* __restrict__ p,
                                                        ushort_t* __restrict__ o) {
  int i = blockIdx.x * 256 + threadIdx.x;  // 65536 float4s
  const float4* p4 = (const float4*)p;
  float4 a = p4[i], b = p4[i + 65536], c = p4[i + 131072], d = p4[i + 196608];
  ushort4_t r;
  r.x = f2bf(a.x + b.x + c.x + d.x);
  r.y = f2bf(a.y + b.y + c.y + d.y);
  r.z = f2bf(a.z + b.z + c.z + d.z);
  r.w = f2bf(a.w + b.w + c.w + d.w);
  ((ushort4_t*)o)[i] = r;
}

// ======================= LayerNorm (wave per row, D=512) -> bf16 =======================
__global__ __launch_bounds__(256) void ln_kernel(
    const float* __restrict__ x, const float* __restrict__ w,
    const float* __restrict__ b, ushort_t* __restrict__ o) {
  int row = blockIdx.x * 4 + (threadIdx.x >> 6);
  int lane = threadIdx.x & 63;
  const float* xr = x + (long)row * DD + lane * 8;
  float v[8];
  *(float4*)&v[0] = *(const float4*)&xr[0];
  *(float4*)&v[4] = *(const float4*)&xr[4];
  float s = 0.f, qq = 0.f;
#pragma unroll
  for (int k = 0; k < 8; ++k) { s += v[k]; qq += v[k] * v[k]; }
#pragma unroll
  for (int off = 1; off < 64; off <<= 1) {
    s += __shfl_xor(s, off);
    qq += __shfl_xor(qq, off);
  }
  float mean = s * (1.f / DD);
  float rs = rsqrtf(qq * (1.f / DD) - mean * mean + 1e-5f);
  int c = lane * 8;
  short8 ov;
#pragma unroll
  for (int k = 0; k < 8; ++k)
    ov[k] = (short)f2bf((v[k] - mean) * rs * w[c + k] + b[c + k]);
  *(short8*)&o[(long)row * DD + c] = ov;
}

// ============== InstanceNorm over L + SiLU, in place (f32) ==============
__global__ __launch_bounds__(256) void inorm_silu_kernel(float* __restrict__ h) {
  long row = blockIdx.x;
  float* p = h + row * (long)LL;
  int t = threadIdx.x;
  float4 v = *(const float4*)&p[t * 4];
  float s = v.x + v.y + v.z + v.w;
  float q = v.x * v.x + v.y * v.y + v.z * v.z + v.w * v.w;
#pragma unroll
  for (int off = 1; off < 64; off <<= 1) {
    s += __shfl_xor(s, off);
    q += __shfl_xor(q, off);
  }
  __shared__ float ss[4], sq[4];
  int wv = t >> 6;
  if ((t & 63) == 0) { ss[wv] = s; sq[wv] = q; }
  __syncthreads();
  s = ss[0] + ss[1] + ss[2] + ss[3];
  q = sq[0] + sq[1] + sq[2] + sq[3];
  float mean = s * (1.f / LL);
  float rs = rsqrtf(q * (1.f / LL) - mean * mean + 1e-5f);
  v.x = silu_f((v.x - mean) * rs);
  v.y = silu_f((v.y - mean) * rs);
  v.z = silu_f((v.z - mean) * rs);
  v.w = silu_f((v.w - mean) * rs);
  *(float4*)&p[t * 4] = v;
}

// ============== Mamba causal depthwise conv (KC=4) + bias + SiLU (bf16 in/out) ==============
__global__ __launch_bounds__(256) void mconv_kernel(
    const ushort_t* __restrict__ xz, const float* __restrict__ cw,
    const float* __restrict__ cb, ushort_t* __restrict__ xc) {
  long i = (long)blockIdx.x * 256 + threadIdx.x;  // over B*L*DI
  int d = (int)(i & (DI - 1));
  long bt = i >> 10;
  int t = (int)(bt & (LL - 1));
  const ushort_t* col = xz + d;
  long r = bt * (2 * DI);
  float w0 = cw[d * 4 + 0], w1 = cw[d * 4 + 1], w2 = cw[d * 4 + 2], w3 = cw[d * 4 + 3];
  float acc = cb[d];
  if (t >= 3) acc += bf2f(col[r - 3 * 2 * DI]) * w0;
  if (t >= 2) acc += bf2f(col[r - 2 * 2 * DI]) * w1;
  if (t >= 1) acc += bf2f(col[r - 1 * 2 * DI]) * w2;
  acc += bf2f(col[r]) * w3;
  xc[i] = f2bf(silu_f(acc));
}

// ============== bf16 transpose (B,L,D=1024) -> (D, B*L): xc -> xc_T ==============
__global__ void transpose_bf_kernel(const ushort_t* __restrict__ in, ushort_t* __restrict__ out) {
  __shared__ ushort_t tile[32][33];
  int b = blockIdx.z;
  int l0 = blockIdx.x * 32, d0 = blockIdx.y * 32;
  int tx = threadIdx.x, ty = threadIdx.y;  // (32, 8)
#pragma unroll
  for (int r = 0; r < 4; ++r)
    tile[ty + 8 * r][tx] = in[((long)b * LL + l0 + ty + 8 * r) * DI + d0 + tx];
  __syncthreads();
#pragma unroll
  for (int r = 0; r < 4; ++r)
    out[(long)(d0 + ty + 8 * r) * (BB * LL) + b * LL + l0 + tx] = tile[tx][ty + 8 * r];
}

// ======================= fused selective scan (one wave per (b,d)) =======================
// dtT/xcT/sT layout: [d][b*1024 + l]. xdb_bf: [b*1024+l][64] (cols 32..47 B, 48..63 C)
__global__ __launch_bounds__(256) void fscan_kernel(
    const ushort_t* __restrict__ dtT, const ushort_t* __restrict__ xcT,
    const ushort_t* __restrict__ xdb_bf, const float* __restrict__ A_log,
    ushort_t* __restrict__ sT) {
  int wid = (blockIdx.x * 256 + threadIdx.x) >> 6;  // 0..4095
  int lane = threadIdx.x & 63;
  int b = wid >> 10, d = wid & 1023;

  float Ac[NST];
  {
    const float4* ap = (const float4*)(A_log + d * NST);
#pragma unroll
    for (int k = 0; k < 4; ++k) {
      float4 a = ap[k];
      Ac[4 * k + 0] = -__expf(a.x);
      Ac[4 * k + 1] = -__expf(a.y);
      Ac[4 * k + 2] = -__expf(a.z);
      Ac[4 * k + 3] = -__expf(a.w);
    }
  }

  const long tbase = (long)d * (BB * LL) + b * LL + lane * 16;
  float ldts[16], lxs[16];
  {
    short8 d0 = *(const short8*)&dtT[tbase];
    short8 d1 = *(const short8*)&dtT[tbase + 8];
    short8 x0 = *(const short8*)&xcT[tbase];
    short8 x1 = *(const short8*)&xcT[tbase + 8];
#pragma unroll
    for (int j = 0; j < 8; ++j) {
      ldts[j] = bf2f((ushort_t)d0[j]);
      ldts[j + 8] = bf2f((ushort_t)d1[j]);
      lxs[j] = bf2f((ushort_t)x0[j]);
      lxs[j + 8] = bf2f((ushort_t)x1[j]);
    }
  }

  const long rb = ((long)b * LL + lane * 16) * 64;  // xdb_bf row base
  // ---- pass 1: chunk-local scan (h from 0) ----
  float h[NST];
#pragma unroll
  for (int n = 0; n < NST; ++n) h[n] = 0.f;
  float ds = 0.f;
#pragma unroll
  for (int tt = 0; tt < 16; ++tt) {
    ds += ldts[tt];
    float coef = ldts[tt] * lxs[tt];
    short8 b0 = *(const short8*)&xdb_bf[rb + tt * 64 + 32];
    short8 b1 = *(const short8*)&xdb_bf[rb + tt * 64 + 40];
#pragma unroll
    for (int n = 0; n < NST; ++n) {
      float bn = bf2f((ushort_t)((n < 8) ? b0[n & 7] : b1[n & 7]));
      h[n] = h[n] * __expf(Ac[n] * ldts[tt]) + coef * bn;
    }
  }

  // ---- wave-level inclusive scan of chunk transforms (A,B) ----
  float av[NST], bv[NST];
#pragma unroll
  for (int n = 0; n < NST; ++n) { av[n] = __expf(Ac[n] * ds); bv[n] = h[n]; }
#pragma unroll
  for (int off = 1; off < 64; off <<= 1) {
    bool ok = (lane >= off);
#pragma unroll
    for (int n = 0; n < NST; ++n) {
      float pa = __shfl_up(av[n], off);
      float pb = __shfl_up(bv[n], off);
      bv[n] = ok ? fmaf(av[n], pb, bv[n]) : bv[n];
      av[n] = ok ? av[n] * pa : av[n];
    }
  }
  // exclusive carry: state at chunk start
#pragma unroll
  for (int n = 0; n < NST; ++n) {
    float c = __shfl_up(bv[n], 1);
    h[n] = (lane == 0) ? 0.f : c;
  }

  // ---- pass 2: replay with carry, emit s = C . h ----
  ushort_t sv[16];
#pragma unroll
  for (int tt = 0; tt < 16; ++tt) {
    float coef = ldts[tt] * lxs[tt];
    short8 b0 = *(const short8*)&xdb_bf[rb + tt * 64 + 32];
    short8 b1 = *(const short8*)&xdb_bf[rb + tt * 64 + 40];
    short8 c0 = *(const short8*)&xdb_bf[rb + tt * 64 + 48];
    short8 c1 = *(const short8*)&xdb_bf[rb + tt * 64 + 56];
    float s = 0.f;
#pragma unroll
    for (int n = 0; n < NST; ++n) {
      float bn = bf2f((ushort_t)((n < 8) ? b0[n & 7] : b1[n & 7]));
      float cn = bf2f((ushort_t)((n < 8) ? c0[n & 7] : c1[n & 7]));
      h[n] = h[n] * __expf(Ac[n] * ldts[tt]) + coef * bn;
      s = fmaf(h[n], cn, s);
    }
    sv[tt] = f2bf(s);
  }
  short8 o0, o1;
#pragma unroll
  for (int j = 0; j < 8; ++j) { o0[j] = (short)sv[j]; o1[j] = (short)sv[j + 8]; }
  *(short8*)&sT[tbase] = o0;
  *(short8*)&sT[tbase + 8] = o1;
}

// ======= gate + untranspose: y[b,l,d] = (sT[d,bl] + xc*D) * silu(z) =======
__global__ void gate_kernel(const ushort_t* __restrict__ sT, const ushort_t* __restrict__ xc,
                            const ushort_t* __restrict__ xz, const float* __restrict__ Dp,
                            ushort_t* __restrict__ y) {
  __shared__ ushort_t tile[32][33];
  int b = blockIdx.z;
  int l0 = blockIdx.x * 32, d0 = blockIdx.y * 32;
  int tx = threadIdx.x, ty = threadIdx.y;  // (32, 8)
#pragma unroll
  for (int r = 0; r < 4; ++r)
    tile[ty + 8 * r][tx] = sT[(long)(d0 + ty + 8 * r) * (BB * LL) + b * LL + l0 + tx];
  __syncthreads();
#pragma unroll
  for (int r = 0; r < 4; ++r) {
    int l = l0 + ty + 8 * r, d = d0 + tx;
    long row = (long)b * LL + l;
    float s = bf2f(tile[tx][ty + 8 * r]);
    float lx = bf2f(xc[row * DI + d]);
    float zv = bf2f(xz[row * (2 * DI) + DI + d]);
    y[row * DI + d] = f2bf((s + lx * Dp[d]) * silu_f(zv));
  }
}

// ============== local depthwise conv over L, 'same' padding (f32) ==============
template <int KW>
__global__ __launch_bounds__(256) void dwconv_kernel(
    const float* __restrict__ in, const float* __restrict__ w, float* __restrict__ out) {
  long i = (long)blockIdx.x * 256 + threadIdx.x;  // over B*D*L
  int l = (int)(i & (LL - 1));
  long bd = i >> 10;
  int d = (int)(bd & (DD - 1));
  const float* row = in + bd * (long)LL;
  float acc = 0.f;
#pragma unroll
  for (int j = 0; j < KW; ++j) {
    int ll = l + j - KW / 2;
    if (ll >= 0 && ll < LL) acc += row[ll] * w[d * KW + j];
  }
  out[i] = acc;
}

// ============== transpose (B, D, L) f32 -> (B, L, D) bf16 ==============
__global__ void transpose_dl_kernel(const float* __restrict__ in, ushort_t* __restrict__ out) {
  __shared__ float tile[32][33];
  int b = blockIdx.z;
  int l0 = blockIdx.x * 32, d0 = blockIdx.y * 32;
  int tx = threadIdx.x, ty = threadIdx.y;  // (32, 8)
  const float* ib = in + (long)b * DD * LL;
  ushort_t* ob = out + (long)b * LL * DD;
#pragma unroll
  for (int r = 0; r < 4; ++r)
    tile[ty + 8 * r][tx] = ib[(long)(d0 + ty + 8 * r) * LL + l0 + tx];
  __syncthreads();
#pragma unroll
  for (int r = 0; r < 4; ++r)
    ob[(long)(l0 + ty + 8 * r) * DD + d0 + tx] = f2bf(tile[tx][ty + 8 * r]);
}

// ============== g (f32) -> cat bf16 columns [0,512) ==============
__global__ __launch_bounds__(256) void copyg_kernel(const float* __restrict__ g,
                                                    ushort_t* __restrict__ cat) {
  long i = (long)blockIdx.x * 256 + threadIdx.x;  // 4096*512
  long r = i >> 9;
  int c = (int)(i & 511);
  cat[r * 1536 + c] = f2bf(g[i]);
}

// ======================= host launch =======================
extern "C" void kernel_launch(void* const* d_in, const int* in_sizes, int n_in,
                              void* d_out, int out_size, void* d_ws, size_t ws_size,
                              hipStream_t stream) {
  const float* x        = (const float*)d_in[0];
  const float* in_w     = (const float*)d_in[1];
  const float* in_b     = (const float*)d_in[2];
  const float* conv_w   = (const float*)d_in[3];
  const float* conv_b   = (const float*)d_in[4];
  const float* xp_w     = (const float*)d_in[5];
  const float* dt_w     = (const float*)d_in[6];
  const float* dt_b     = (const float*)d_in[7];
  const float* A_log    = (const float*)d_in[8];
  const float* Dp       = (const float*)d_in[9];
  const float* out_w    = (const float*)d_in[10];
  const float* out_b    = (const float*)d_in[11];
  const float* ln_w     = (const float*)d_in[12];
  const float* ln_b     = (const float*)d_in[13];
  const float* ffn_ln_w = (const float*)d_in[14];
  const float* ffn_ln_b = (const float*)d_in[15];
  const float* ffn_w1   = (const float*)d_in[16];
  const float* ffn_b1   = (const float*)d_in[17];
  const float* ffn_w2   = (const float*)d_in[18];
  const float* ffn_b2   = (const float*)d_in[19];
  const float* l5_pw1w  = (const float*)d_in[20];
  const float* l5_pw1b  = (const float*)d_in[21];
  const float* l5_dww   = (const float*)d_in[22];
  const float* l5_pw2w  = (const float*)d_in[23];
  const float* l5_pw2b  = (const float*)d_in[24];
  const float* l7_pw1w  = (const float*)d_in[25];
  const float* l7_pw1b  = (const float*)d_in[26];
  const float* l7_dww   = (const float*)d_in[27];
  const float* l7_pw2w  = (const float*)d_in[28];
  const float* l7_pw2b  = (const float*)d_in[29];
  const float* proj_w   = (const float*)d_in[30];
  const float* proj_b   = (const float*)d_in[31];
  float* outp = (float*)d_out;

  // ---------- workspace layout ----------
  const long N_BLD = (long)BB * LL * DD;  // 2,097,152
  ushort_t* wb_in  = (ushort_t*)d_ws;          // 4,194,304
  ushort_t* wb_out = wb_in + 4194304;          // 2,097,152
  ushort_t* wb_xp  = wb_out + 2097152;         // 262,144 (4 x 64 x 1024)
  ushort_t* wb_dtw = wb_xp + 262144;           // 262,144 (4 x 1024 x 64, zero-padded)
  ushort_t* wb_f1  = wb_dtw + 262144;          // 2,097,152
  ushort_t* wb_f2  = wb_f1 + 2097152;          // 2,097,152
  ushort_t* wb_pw1 = wb_f2 + 2097152;          // 524,288 (k5 @0, k7 @262144)
  ushort_t* wb_pw2 = wb_pw1 + 524288;          // 524,288
  ushort_t* wb_proj= wb_pw2 + 524288;          // 786,432
  ushort_t* xnb    = wb_proj + 786432;         // 2,097,152 bf16
  float* g = (float*)(xnb + 2097152);          // 2,097,152 f32
  char* arena = (char*)(g + 2097152);
  // mamba/ffn phase
  ushort_t* xzb = (ushort_t*)arena;            // 8,388,608 ush (4096 x 2048)
  ushort_t* xcb = xzb + 8388608;               // 4,194,304 ush
  ushort_t* xcT = xcb + 4194304;               // 4,194,304 ush (1024 x 4096)
  ushort_t* dtT = xcT + 4194304;               // 4,194,304 ush (1024 x 4096)
  ushort_t* sT  = dtT + 4194304;               // 4,194,304 ush (1024 x 4096)
  ushort_t* yb  = sT + 4194304;                // 4,194,304 ush
  ushort_t* xdb_bf = yb + 4194304;             // 262,144 ush (4096 x 64)
  float* xdbp = (float*)(xdb_bf + 262144);     // 1,048,576 f32 (xproj partials)
  ushort_t* h1b = xcT;                         // 8,388,608 ush (FFN h1; xcT+dtT dead by FFN)
  // locals overlay (mamba scratch dead)
  ushort_t* xbf = (ushort_t*)arena;            // 2,097,152 ush
  float* lh  = (float*)(xbf + 2097152);        // 2,097,152 f32
  float* lhc = lh + 2097152;                   // 2,097,152 f32
  ushort_t* lhT = (ushort_t*)(lhc + 2097152);  // 2,097,152 ush
  ushort_t* cat = lhT + 2097152;               // 6,291,456 ush
  size_t need = (size_t)((char*)(xdbp + 1048576) - (char*)d_ws);
  if (ws_size < need) return;

  // ---------- fused weight conversions (bf16) ----------
  {
    CvtArgs ca;
    const float* srcs[NSEG] = {in_w, out_w, xp_w, ffn_w1, ffn_w2,
                               l5_pw1w, l7_pw1w, l5_pw2w, l7_pw2w, proj_w};
    ushort_t* dsts[NSEG] = {wb_in, wb_out, wb_xp, wb_f1, wb_f2,
                            wb_pw1, wb_pw1 + 262144, wb_pw2, wb_pw2 + 262144, wb_proj};
    int cnt4[NSEG] = {4194304 / 4, 2097152 / 4, 262144 / 4, 2097152 / 4, 2097152 / 4,
                      262144 / 4, 262144 / 4, 262144 / 4, 262144 / 4, 786432 / 4};
    int acc = 0;
    for (int s = 0; s < NSEG; ++s) { ca.src[s] = srcs[s]; ca.dst[s] = dsts[s]; ca.start4[s] = acc; acc += cnt4[s]; }
    cvt_all_kernel<<<2048, 256, 0, stream>>>(ca, acc);
  }
  cvtpad_dtw_kernel<<<1024, 256, 0, stream>>>(dt_w, wb_dtw);

  hipMemcpyAsync(g, x, N_BLD * 4, hipMemcpyDeviceToDevice, stream);

  const long sBL = (long)LL * DD;  // 524288
  for (int i = 0; i < 2; ++i) {
    ln_kernel<<<1024, 256, 0, stream>>>(g, ln_w + i * 512, ln_b + i * 512, xnb);
    for (int dir = 0; dir < 2; ++dir) {
      int m = 2 * i + dir;
      const ushort_t* wi = wb_in + (long)m * 1048576;
      const float* bi = in_b + (long)m * 2048;
      // in-proj: 4096 x 2048 x 512 -> xzb (bf16)
      if (dir == 0)
        mgemm<128, 0, 1, 0, 0, 0, 1, 0><<<dim3(16, 32, 1), 256, 0, stream>>>(
            xnb, wi, bi, xzb, 512, 512, 512, 2048, 2048, 0, 0, 0, 1.f);
      else
        mgemm<128, 0, 1, 0, 1, 0, 1, 0><<<dim3(16, 32, 1), 256, 0, stream>>>(
            xnb, wi, bi, xzb, 512, 512, 512, 2048, 2048, 0, 0, 0, 1.f);
      mconv_kernel<<<16384, 256, 0, stream>>>(xzb, conv_w + (long)m * 4096,
                                              conv_b + (long)m * 1024, xcb);
      transpose_bf_kernel<<<dim3(32, 32, 4), dim3(32, 8), 0, stream>>>(xcb, xcT);
      // xproj: 4096 x 64 x 1024, split-K x4 -> f32 partials, reduce -> bf16 xdb
      mgemm<64, 0, 0, 0, 0, 0, 0, 1><<<dim3(1, 32, 4), 256, 0, stream>>>(
          xcb, wb_xp + (long)m * 65536, nullptr, xdbp, 256, 1024, 1024, 64, 64,
          0, 0, 262144, 1.f);
      reduce4bf_kernel<<<256, 256, 0, stream>>>(xdbp, xdb_bf);
      // dt-proj (transposed): dtT(1024 x 4096) = softplus(dtw_pad x xdb_bf^T + dt_b)
      mgemm<128, 3, 2, 0, 0, 0, 1, 0><<<dim3(32, 8, 1), 256, 0, stream>>>(
          wb_dtw + (long)m * 65536, xdb_bf, dt_b + (long)m * 1024, dtT,
          64, 64, 64, 4096, 4096, 0, 0, 0, 1.f);
      // fused scan (pass1 + wave butterfly + pass2)
      fscan_kernel<<<1024, 256, 0, stream>>>(dtT, xcT, xdb_bf,
                                             A_log + (long)m * 16384, sT);
      // gate + untranspose -> yb (b,l,d)
      gate_kernel<<<dim3(32, 32, 4), dim3(32, 8), 0, stream>>>(
          sT, xcb, xzb, Dp + (long)m * 1024, yb);
      // out-proj: 4096 x 512 x 1024, g += 0.5*(...)
      if (dir == 0)
        mgemm<64, 0, 1, 1, 0, 0, 0, 0><<<dim3(8, 32, 1), 256, 0, stream>>>(
            yb, wb_out + (long)m * 524288, out_b + (long)m * 512, g, 1024, 1024, 1024, 512,
            512, 0, 0, 0, 0.5f);
      else
        mgemm<64, 0, 1, 1, 0, 1, 0, 0><<<dim3(8, 32, 1), 256, 0, stream>>>(
            yb, wb_out + (long)m * 524288, out_b + (long)m * 512, g, 1024, 1024, 1024, 512,
            512, 0, 0, 0, 0.5f);
    }
    // FFN
    ln_kernel<<<1024, 256, 0, stream>>>(g, ffn_ln_w + i * 512, ffn_ln_b + i * 512, xnb);
    mgemm<128, 2, 1, 0, 0, 0, 1, 0><<<dim3(16, 32, 1), 256, 0, stream>>>(
        xnb, wb_f1 + (long)i * 1048576, ffn_b1 + (long)i * 2048, h1b, 512, 512, 512, 2048,
        2048, 0, 0, 0, 1.f);
    mgemm<64, 0, 1, 1, 0, 0, 0, 0><<<dim3(8, 32, 1), 256, 0, stream>>>(
        h1b, wb_f2 + (long)i * 1048576, ffn_b2 + (long)i * 512, g, 2048, 2048, 2048, 512,
        512, 0, 0, 0, 1.f);
  }

  // ---------- locals ----------
  cvt_kernel<<<512, 256, 0, stream>>>(x, xbf, N_BLD);
  for (int k = 0; k < 2; ++k) {
    const ushort_t* pw1w = wb_pw1 + (long)k * 262144;
    const float* pw1b = k ? l7_pw1b : l5_pw1b;
    const float* dww  = k ? l7_dww  : l5_dww;
    const ushort_t* pw2w = wb_pw2 + (long)k * 262144;
    const float* pw2b = k ? l7_pw2b : l5_pw2b;
    // pw1: per batch  lh[b](D,L) = W(512x512) x xbf[b](1024x512)^T
    mgemm<64, 0, 2, 0, 0, 0, 0, 0><<<dim3(16, 4, 4), 256, 0, stream>>>(
        pw1w, xbf, pw1b, lh, 512, 512, 512, 1024, 1024, 0, sBL, sBL, 1.f);
    inorm_silu_kernel<<<2048, 256, 0, stream>>>(lh);
    if (k)
      dwconv_kernel<7><<<8192, 256, 0, stream>>>(lh, dww, lhc);
    else
      dwconv_kernel<5><<<8192, 256, 0, stream>>>(lh, dww, lhc);
    inorm_silu_kernel<<<2048, 256, 0, stream>>>(lhc);
    transpose_dl_kernel<<<dim3(32, 16, 4), dim3(32, 8), 0, stream>>>(lhc, lhT);
    // pw2: per batch  cat[b](1024, cols 512k..512k+512) = lhT[b](1024x512) x W^T -> bf16
    mgemm<64, 0, 1, 0, 0, 0, 1, 0><<<dim3(8, 8, 4), 256, 0, stream>>>(
        lhT, pw2w, pw2b, cat + (k ? 1024 : 512), 512, 512, 512, 1536, 512,
        sBL, 0, (long)LL * 1536, 1.f);
  }
  copyg_kernel<<<8192, 256, 0, stream>>>(g, cat);
  hipMemcpyAsync(outp, x, N_BLD * 4, hipMemcpyDeviceToDevice, stream);
  // out += cat(4096x1536) @ proj_w^T (512x1536)
  mgemm<64, 0, 1, 1, 0, 0, 0, 0><<<dim3(8, 32, 1), 256, 0, stream>>>(
      cat, wb_proj, proj_b, outp, 1536, 1536, 1536, 512, 512, 0, 0, 0, 1.f);
}

// Round 7
// 989.337 us; speedup vs baseline: 1.5526x; 1.5526x over previous
//
#include <hip/hip_runtime.h>
#include <hip/hip_bf16.h>
#include <math.h>

// ---------- problem constants ----------
#define BB 4
#define LL 1024
#define DD 512
#define DI 1024
#define NST 16

typedef unsigned short ushort_t;
typedef __attribute__((ext_vector_type(8))) short short8;
typedef __attribute__((ext_vector_type(4))) float f32x4;
typedef __attribute__((ext_vector_type(4))) unsigned short ushort4_t;

__device__ __forceinline__ float silu_f(float x) { return x / (1.f + __expf(-x)); }

__device__ __forceinline__ ushort_t f2bf(float f) {
  union { float f; unsigned u; } v; v.f = f;
  unsigned r = v.u + 0x7fffu + ((v.u >> 16) & 1u);
  return (ushort_t)(r >> 16);
}
__device__ __forceinline__ float bf2f(ushort_t h) {
  union { unsigned u; float f; } v; v.u = ((unsigned)h) << 16;
  return v.f;
}

__device__ __forceinline__ void gl_lds16(const ushort_t* src, ushort_t* dst) {
  __builtin_amdgcn_global_load_lds(
      (const __attribute__((address_space(1))) void*)src,
      (__attribute__((address_space(3))) void*)dst, 16, 0, 0);
}

// ======================= bf16 MFMA GEMM (2-phase double-buffered) =======================
// C[m,n] = op( sum_k A[m,k]*Bt[n,k] + bias );  A: M x K bf16, Bt: N x K bf16
// BM=128, BK=64, 4 waves. BN=128: wave grid 2x2 (64x64/wave). BN=64: 4x1 (32x64).
// ACT: 0 none 1 silu 2 gelu 3 softplus ; BIASM: 0 none 1 col 2 row
// CMODE: 0 store, 1 += (f32) ; FLIPA/FLIPC: row ^ 1023 ; OUTBF: C bf16
// SPLITK: blockIdx.z = k-split; A/B advance zz*K, C advances zz*sC (partials)
template <int BN, int ACT, int BIASM, int CMODE, int FLIPA, int FLIPC, int OUTBF, int SPLITK>
__global__ __launch_bounds__(256) void mgemm(
    const ushort_t* __restrict__ A, const ushort_t* __restrict__ Bt,
    const float* __restrict__ bias, void* __restrict__ Cv,
    int K, int lda, int ldb, int ldc, int nreal,
    long sA, long sB, long sC, float scale) {
  constexpr int MREP = (BN == 128) ? 4 : 2;
  constexpr int WM = MREP * 16;
  constexpr int NB = BN / 32;
  __shared__ ushort_t As[2][128 * 64];
  __shared__ ushort_t Bs[2][BN * 64];
  const int zz = blockIdx.z;
  const ushort_t* Ab = A + (SPLITK ? (long)zz * K : zz * sA);
  const ushort_t* Bb = Bt + (SPLITK ? (long)zz * K : zz * sB);
  const int flat = blockIdx.y * gridDim.x + blockIdx.x;
  const int nwg = gridDim.x * gridDim.y;
  const int id2 = (flat & 7) * (nwg >> 3) + (flat >> 3);
  const int bm = (id2 / gridDim.x) * 128;
  const int bn = (id2 % gridDim.x) * BN;
  const int tid = threadIdx.x;
  const int wave = tid >> 6, lane = tid & 63;
  const int rlo = lane & 15, q = lane >> 4;
  const int wr = (BN == 128) ? (wave >> 1) : wave;
  const int wc = (BN == 128) ? (wave & 1) : 0;

  f32x4 zero4 = {0.f, 0.f, 0.f, 0.f};
  f32x4 acc[MREP][4];
#pragma unroll
  for (int m = 0; m < MREP; ++m)
#pragma unroll
    for (int n = 0; n < 4; ++n) acc[m][n] = zero4;

  const int srow_off = lane >> 3;
  const int sslot = lane & 7;

#define STAGE_T(bb, k0)                                          \
  do {                                                           \
    _Pragma("unroll") for (int it = 0; it < 4; ++it) {           \
      int c = wave * 4 + it;                                     \
      int row = c * 8 + srow_off;                                \
      int gcol = ((sslot ^ (row & 7)) << 3);                     \
      int gra = bm + row;                                        \
      if (FLIPA) gra ^= 1023;                                    \
      gl_lds16(Ab + (long)gra * lda + (k0) + gcol, &As[bb][c * 512]); } \
    _Pragma("unroll") for (int it = 0; it < NB; ++it) {          \
      int c = wave * NB + it;                                    \
      int row = c * 8 + srow_off;                                \
      int gcol = ((sslot ^ (row & 7)) << 3);                     \
      gl_lds16(Bb + (long)(bn + row) * ldb + (k0) + gcol, &Bs[bb][c * 512]); } \
  } while (0)

  const int nt = K >> 6;
  STAGE_T(0, 0);
  __syncthreads();
  int cur = 0;
  for (int t = 0; t < nt; ++t) {
    if (t + 1 < nt) STAGE_T(cur ^ 1, (t + 1) * 64);
#pragma unroll
    for (int ks = 0; ks < 2; ++ks) {
      short8 af[MREP], bf[4];
#pragma unroll
      for (int m = 0; m < MREP; ++m) {
        int row = wr * WM + m * 16 + rlo;
        int ch = (ks * 4 + q) ^ (row & 7);
        af[m] = *(const short8*)&As[cur][row * 64 + ch * 8];
      }
#pragma unroll
      for (int n = 0; n < 4; ++n) {
        int row = wc * 64 + n * 16 + rlo;
        int ch = (ks * 4 + q) ^ (row & 7);
        bf[n] = *(const short8*)&Bs[cur][row * 64 + ch * 8];
      }
#pragma unroll
      for (int m = 0; m < MREP; ++m)
#pragma unroll
        for (int n = 0; n < 4; ++n)
          acc[m][n] = __builtin_amdgcn_mfma_f32_16x16x32_bf16(af[m], bf[n], acc[m][n], 0, 0, 0);
    }
    __syncthreads();
    cur ^= 1;
  }
#undef STAGE_T

#pragma unroll
  for (int m = 0; m < MREP; ++m) {
#pragma unroll
    for (int n = 0; n < 4; ++n) {
      int col = bn + wc * 64 + n * 16 + rlo;
      bool cok = (col < nreal);
#pragma unroll
      for (int j = 0; j < 4; ++j) {
        int row = bm + wr * WM + m * 16 + q * 4 + j;
        int orow = FLIPC ? (row ^ 1023) : row;
        float v = acc[m][n][j];
        if (!SPLITK || zz == 0) {
          if (BIASM == 1) v += bias[col];
          else if (BIASM == 2) v += bias[row];
        }
        if (ACT == 1) v = silu_f(v);
        else if (ACT == 2) v = 0.5f * v * (1.f + erff(v * 0.70710678118654752f));
        else if (ACT == 3) v = (v > 20.f) ? v : log1pf(__expf(v));
        if (cok) {
          if (OUTBF) {
            ushort_t* C = (ushort_t*)Cv + (long)zz * sC;
            C[(long)orow * ldc + col] = f2bf(scale * v);
          } else {
            float* C = (float*)Cv + (long)zz * sC;
            if (CMODE == 1) C[(long)orow * ldc + col] += scale * v;
            else C[(long)orow * ldc + col] = scale * v;
          }
        }
      }
    }
  }
}

// ======================= fused f32 -> bf16 weight conversion =======================
#define NSEG 10
struct CvtArgs {
  const float* src[NSEG];
  ushort_t* dst[NSEG];
  int start4[NSEG];
};
__global__ __launch_bounds__(256) void cvt_all_kernel(CvtArgs a, int total4) {
  int i = blockIdx.x * 256 + threadIdx.x;
  int stride = gridDim.x * 256;
  for (; i < total4; i += stride) {
    int seg = 0;
#pragma unroll
    for (int s = 1; s < NSEG; ++s)
      if (i >= a.start4[s]) seg = s;
    int off = i - a.start4[seg];
    float4 v = ((const float4*)a.src[seg])[off];
    ushort4_t o;
    o.x = f2bf(v.x); o.y = f2bf(v.y); o.z = f2bf(v.z); o.w = f2bf(v.w);
    *(ushort4_t*)(a.dst[seg] + (long)off * 4) = o;
  }
}

// dt_w (4 x 1024 x 32) f32 -> padded bf16 (4 x 1024 x 64), cols >=32 zero
__global__ __launch_bounds__(256) void cvtpad_dtw_kernel(const float* __restrict__ in,
                                                         ushort_t* __restrict__ out) {
  int i = blockIdx.x * 256 + threadIdx.x;  // 262144
  int k = i & 63;
  int dm = i >> 6;
  out[i] = (k < 32) ? f2bf(in[dm * 32 + k]) : (ushort_t)0;
}

// plain cvt (x -> bf16, locals phase)
__global__ __launch_bounds__(256) void cvt_kernel(const float* __restrict__ in,
                                                  ushort_t* __restrict__ out, long n) {
  long i = (long)blockIdx.x * 256 + threadIdx.x;
  long stride = (long)gridDim.x * 256;
  for (; i < n; i += stride) out[i] = f2bf(in[i]);
}

// ======================= reduce 4 split-K partials -> bf16 =======================
__global__ __launch_bounds__(256) void reduce4bf_kernel(const float* __restrict__ p,
                                                        ushort_t* __restrict__ o) {
  int i = blockIdx.x * 256 + threadIdx.x;  // 65536 float4s
  const float4* p4 = (const float4*)p;
  float4 a = p4[i], b = p4[i + 65536], c = p4[i + 131072], d = p4[i + 196608];
  ushort4_t r;
  r.x = f2bf(a.x + b.x + c.x + d.x);
  r.y = f2bf(a.y + b.y + c.y + d.y);
  r.z = f2bf(a.z + b.z + c.z + d.z);
  r.w = f2bf(a.w + b.w + c.w + d.w);
  ((ushort4_t*)o)[i] = r;
}

// ======================= LayerNorm (wave per row, D=512) -> bf16 =======================
__global__ __launch_bounds__(256) void ln_kernel(
    const float* __restrict__ x, const float* __restrict__ w,
    const float* __restrict__ b, ushort_t* __restrict__ o) {
  int row = blockIdx.x * 4 + (threadIdx.x >> 6);
  int lane = threadIdx.x & 63;
  const float* xr = x + (long)row * DD + lane * 8;
  float v[8];
  *(float4*)&v[0] = *(const float4*)&xr[0];
  *(float4*)&v[4] = *(const float4*)&xr[4];
  float s = 0.f, qq = 0.f;
#pragma unroll
  for (int k = 0; k < 8; ++k) { s += v[k]; qq += v[k] * v[k]; }
#pragma unroll
  for (int off = 1; off < 64; off <<= 1) {
    s += __shfl_xor(s, off);
    qq += __shfl_xor(qq, off);
  }
  float mean = s * (1.f / DD);
  float rs = rsqrtf(qq * (1.f / DD) - mean * mean + 1e-5f);
  int c = lane * 8;
  short8 ov;
#pragma unroll
  for (int k = 0; k < 8; ++k)
    ov[k] = (short)f2bf((v[k] - mean) * rs * w[c + k] + b[c + k]);
  *(short8*)&o[(long)row * DD + c] = ov;
}

// ============== InstanceNorm over L + SiLU, in place (f32) ==============
__global__ __launch_bounds__(256) void inorm_silu_kernel(float* __restrict__ h) {
  long row = blockIdx.x;
  float* p = h + row * (long)LL;
  int t = threadIdx.x;
  float4 v = *(const float4*)&p[t * 4];
  float s = v.x + v.y + v.z + v.w;
  float q = v.x * v.x + v.y * v.y + v.z * v.z + v.w * v.w;
#pragma unroll
  for (int off = 1; off < 64; off <<= 1) {
    s += __shfl_xor(s, off);
    q += __shfl_xor(q, off);
  }
  __shared__ float ss[4], sq[4];
  int wv = t >> 6;
  if ((t & 63) == 0) { ss[wv] = s; sq[wv] = q; }
  __syncthreads();
  s = ss[0] + ss[1] + ss[2] + ss[3];
  q = sq[0] + sq[1] + sq[2] + sq[3];
  float mean = s * (1.f / LL);
  float rs = rsqrtf(q * (1.f / LL) - mean * mean + 1e-5f);
  v.x = silu_f((v.x - mean) * rs);
  v.y = silu_f((v.y - mean) * rs);
  v.z = silu_f((v.z - mean) * rs);
  v.w = silu_f((v.w - mean) * rs);
  *(float4*)&p[t * 4] = v;
}

// ============== Mamba causal depthwise conv (KC=4) + bias + SiLU (bf16 in/out) ==============
__global__ __launch_bounds__(256) void mconv_kernel(
    const ushort_t* __restrict__ xz, const float* __restrict__ cw,
    const float* __restrict__ cb, ushort_t* __restrict__ xc) {
  long i = (long)blockIdx.x * 256 + threadIdx.x;  // over B*L*DI
  int d = (int)(i & (DI - 1));
  long bt = i >> 10;
  int t = (int)(bt & (LL - 1));
  const ushort_t* col = xz + d;
  long r = bt * (2 * DI);
  float w0 = cw[d * 4 + 0], w1 = cw[d * 4 + 1], w2 = cw[d * 4 + 2], w3 = cw[d * 4 + 3];
  float acc = cb[d];
  if (t >= 3) acc += bf2f(col[r - 3 * 2 * DI]) * w0;
  if (t >= 2) acc += bf2f(col[r - 2 * 2 * DI]) * w1;
  if (t >= 1) acc += bf2f(col[r - 1 * 2 * DI]) * w2;
  acc += bf2f(col[r]) * w3;
  xc[i] = f2bf(silu_f(acc));
}

// ============== bf16 transpose (B,L,D=1024) -> (D, B*L): xc -> xc_T ==============
__global__ void transpose_bf_kernel(const ushort_t* __restrict__ in, ushort_t* __restrict__ out) {
  __shared__ ushort_t tile[32][33];
  int b = blockIdx.z;
  int l0 = blockIdx.x * 32, d0 = blockIdx.y * 32;
  int tx = threadIdx.x, ty = threadIdx.y;  // (32, 8)
#pragma unroll
  for (int r = 0; r < 4; ++r)
    tile[ty + 8 * r][tx] = in[((long)b * LL + l0 + ty + 8 * r) * DI + d0 + tx];
  __syncthreads();
#pragma unroll
  for (int r = 0; r < 4; ++r)
    out[(long)(d0 + ty + 8 * r) * (BB * LL) + b * LL + l0 + tx] = tile[tx][ty + 8 * r];
}

// ======================= fused selective scan (one wave per (b,d)) =======================
// dtT/xcT/sT layout: [d][b*1024 + l]. xdb_bf: [b*1024+l][64] (cols 32..47 B, 48..63 C)
// Register-pressure-conscious: no dt/xc preload arrays, outer groups unroll(1),
// butterfly in-place on h[].
__global__ __launch_bounds__(256) void fscan_kernel(
    const ushort_t* __restrict__ dtT, const ushort_t* __restrict__ xcT,
    const ushort_t* __restrict__ xdb_bf, const float* __restrict__ A_log,
    ushort_t* __restrict__ sT) {
  int wid = (blockIdx.x * 256 + threadIdx.x) >> 6;  // 0..4095
  int lane = threadIdx.x & 63;
  int b = wid >> 10, d = wid & 1023;

  float Ac[NST];
  {
    const float4* ap = (const float4*)(A_log + d * NST);
#pragma unroll
    for (int k = 0; k < 4; ++k) {
      float4 a = ap[k];
      Ac[4 * k + 0] = -__expf(a.x);
      Ac[4 * k + 1] = -__expf(a.y);
      Ac[4 * k + 2] = -__expf(a.z);
      Ac[4 * k + 3] = -__expf(a.w);
    }
  }

  const long tbase = (long)d * (BB * LL) + b * LL + lane * 16;
  const long rb = ((long)b * LL + lane * 16) * 64;  // xdb_bf row base

  // ---- pass 1: chunk-local scan (h from 0) ----
  float h[NST];
#pragma unroll
  for (int n = 0; n < NST; ++n) h[n] = 0.f;
  float ds = 0.f;
#pragma unroll 1
  for (int jj = 0; jj < 2; ++jj) {
    short8 dv = *(const short8*)&dtT[tbase + jj * 8];
    short8 xv = *(const short8*)&xcT[tbase + jj * 8];
#pragma unroll
    for (int t8 = 0; t8 < 8; ++t8) {
      int tt = jj * 8 + t8;
      float ldt = bf2f((ushort_t)dv[t8]);
      float lx = bf2f((ushort_t)xv[t8]);
      ds += ldt;
      float coef = ldt * lx;
      short8 b0 = *(const short8*)&xdb_bf[rb + tt * 64 + 32];
      short8 b1 = *(const short8*)&xdb_bf[rb + tt * 64 + 40];
#pragma unroll
      for (int n = 0; n < NST; ++n) {
        float bn = bf2f((ushort_t)((n < 8) ? b0[n & 7] : b1[n & 7]));
        h[n] = h[n] * __expf(Ac[n] * ldt) + coef * bn;
      }
    }
  }

  // ---- wave-level inclusive scan of chunk transforms, in place on h ----
  {
    float av[NST];
#pragma unroll
    for (int n = 0; n < NST; ++n) av[n] = __expf(Ac[n] * ds);
#pragma unroll
    for (int off = 1; off < 64; off <<= 1) {
      bool ok = (lane >= off);
#pragma unroll
      for (int n = 0; n < NST; ++n) {
        float pa = __shfl_up(av[n], off);
        float pb = __shfl_up(h[n], off);
        h[n] = ok ? fmaf(av[n], pb, h[n]) : h[n];
        av[n] = ok ? av[n] * pa : av[n];
      }
    }
    // exclusive carry: state at chunk start
#pragma unroll
    for (int n = 0; n < NST; ++n) {
      float c = __shfl_up(h[n], 1);
      h[n] = (lane == 0) ? 0.f : c;
    }
  }

  // ---- pass 2: replay with carry, emit s = C . h ----
#pragma unroll 1
  for (int jj = 0; jj < 2; ++jj) {
    short8 dv = *(const short8*)&dtT[tbase + jj * 8];
    short8 xv = *(const short8*)&xcT[tbase + jj * 8];
    short8 ov;
#pragma unroll
    for (int t8 = 0; t8 < 8; ++t8) {
      int tt = jj * 8 + t8;
      float ldt = bf2f((ushort_t)dv[t8]);
      float lx = bf2f((ushort_t)xv[t8]);
      float coef = ldt * lx;
      short8 b0 = *(const short8*)&xdb_bf[rb + tt * 64 + 32];
      short8 b1 = *(const short8*)&xdb_bf[rb + tt * 64 + 40];
      short8 c0 = *(const short8*)&xdb_bf[rb + tt * 64 + 48];
      short8 c1 = *(const short8*)&xdb_bf[rb + tt * 64 + 56];
      float s = 0.f;
#pragma unroll
      for (int n = 0; n < NST; ++n) {
        float bn = bf2f((ushort_t)((n < 8) ? b0[n & 7] : b1[n & 7]));
        float cn = bf2f((ushort_t)((n < 8) ? c0[n & 7] : c1[n & 7]));
        h[n] = h[n] * __expf(Ac[n] * ldt) + coef * bn;
        s = fmaf(h[n], cn, s);
      }
      ov[t8] = (short)f2bf(s);
    }
    *(short8*)&sT[tbase + jj * 8] = ov;
  }
}

// ======= gate + untranspose: y[b,l,d] = (sT[d,bl] + xc*D) * silu(z) =======
__global__ void gate_kernel(const ushort_t* __restrict__ sT, const ushort_t* __restrict__ xc,
                            const ushort_t* __restrict__ xz, const float* __restrict__ Dp,
                            ushort_t* __restrict__ y) {
  __shared__ ushort_t tile[32][33];
  int b = blockIdx.z;
  int l0 = blockIdx.x * 32, d0 = blockIdx.y * 32;
  int tx = threadIdx.x, ty = threadIdx.y;  // (32, 8)
#pragma unroll
  for (int r = 0; r < 4; ++r)
    tile[ty + 8 * r][tx] = sT[(long)(d0 + ty + 8 * r) * (BB * LL) + b * LL + l0 + tx];
  __syncthreads();
#pragma unroll
  for (int r = 0; r < 4; ++r) {
    int l = l0 + ty + 8 * r, d = d0 + tx;
    long row = (long)b * LL + l;
    float s = bf2f(tile[tx][ty + 8 * r]);
    float lx = bf2f(xc[row * DI + d]);
    float zv = bf2f(xz[row * (2 * DI) + DI + d]);
    y[row * DI + d] = f2bf((s + lx * Dp[d]) * silu_f(zv));
  }
}

// ============== local depthwise conv over L, 'same' padding (f32) ==============
template <int KW>
__global__ __launch_bounds__(256) void dwconv_kernel(
    const float* __restrict__ in, const float* __restrict__ w, float* __restrict__ out) {
  long i = (long)blockIdx.x * 256 + threadIdx.x;  // over B*D*L
  int l = (int)(i & (LL - 1));
  long bd = i >> 10;
  int d = (int)(bd & (DD - 1));
  const float* row = in + bd * (long)LL;
  float acc = 0.f;
#pragma unroll
  for (int j = 0; j < KW; ++j) {
    int ll = l + j - KW / 2;
    if (ll >= 0 && ll < LL) acc += row[ll] * w[d * KW + j];
  }
  out[i] = acc;
}

// ============== transpose (B, D, L) f32 -> (B, L, D) bf16 ==============
__global__ void transpose_dl_kernel(const float* __restrict__ in, ushort_t* __restrict__ out) {
  __shared__ float tile[32][33];
  int b = blockIdx.z;
  int l0 = blockIdx.x * 32, d0 = blockIdx.y * 32;
  int tx = threadIdx.x, ty = threadIdx.y;  // (32, 8)
  const float* ib = in + (long)b * DD * LL;
  ushort_t* ob = out + (long)b * LL * DD;
#pragma unroll
  for (int r = 0; r < 4; ++r)
    tile[ty + 8 * r][tx] = ib[(long)(d0 + ty + 8 * r) * LL + l0 + tx];
  __syncthreads();
#pragma unroll
  for (int r = 0; r < 4; ++r)
    ob[(long)(l0 + ty + 8 * r) * DD + d0 + tx] = f2bf(tile[tx][ty + 8 * r]);
}

// ============== g (f32) -> cat bf16 columns [0,512) ==============
__global__ __launch_bounds__(256) void copyg_kernel(const float* __restrict__ g,
                                                    ushort_t* __restrict__ cat) {
  long i = (long)blockIdx.x * 256 + threadIdx.x;  // 4096*512
  long r = i >> 9;
  int c = (int)(i & 511);
  cat[r * 1536 + c] = f2bf(g[i]);
}

// ======================= host launch =======================
extern "C" void kernel_launch(void* const* d_in, const int* in_sizes, int n_in,
                              void* d_out, int out_size, void* d_ws, size_t ws_size,
                              hipStream_t stream) {
  const float* x        = (const float*)d_in[0];
  const float* in_w     = (const float*)d_in[1];
  const float* in_b     = (const float*)d_in[2];
  const float* conv_w   = (const float*)d_in[3];
  const float* conv_b   = (const float*)d_in[4];
  const float* xp_w     = (const float*)d_in[5];
  const float* dt_w     = (const float*)d_in[6];
  const float* dt_b     = (const float*)d_in[7];
  const float* A_log    = (const float*)d_in[8];
  const float* Dp       = (const float*)d_in[9];
  const float* out_w    = (const float*)d_in[10];
  const float* out_b    = (const float*)d_in[11];
  const float* ln_w     = (const float*)d_in[12];
  const float* ln_b     = (const float*)d_in[13];
  const float* ffn_ln_w = (const float*)d_in[14];
  const float* ffn_ln_b = (const float*)d_in[15];
  const float* ffn_w1   = (const float*)d_in[16];
  const float* ffn_b1   = (const float*)d_in[17];
  const float* ffn_w2   = (const float*)d_in[18];
  const float* ffn_b2   = (const float*)d_in[19];
  const float* l5_pw1w  = (const float*)d_in[20];
  const float* l5_pw1b  = (const float*)d_in[21];
  const float* l5_dww   = (const float*)d_in[22];
  const float* l5_pw2w  = (const float*)d_in[23];
  const float* l5_pw2b  = (const float*)d_in[24];
  const float* l7_pw1w  = (const float*)d_in[25];
  const float* l7_pw1b  = (const float*)d_in[26];
  const float* l7_dww   = (const float*)d_in[27];
  const float* l7_pw2w  = (const float*)d_in[28];
  const float* l7_pw2b  = (const float*)d_in[29];
  const float* proj_w   = (const float*)d_in[30];
  const float* proj_b   = (const float*)d_in[31];
  float* outp = (float*)d_out;

  // ---------- workspace layout ----------
  const long N_BLD = (long)BB * LL * DD;  // 2,097,152
  ushort_t* wb_in  = (ushort_t*)d_ws;          // 4,194,304
  ushort_t* wb_out = wb_in + 4194304;          // 2,097,152
  ushort_t* wb_xp  = wb_out + 2097152;         // 262,144 (4 x 64 x 1024)
  ushort_t* wb_dtw = wb_xp + 262144;           // 262,144 (4 x 1024 x 64, zero-padded)
  ushort_t* wb_f1  = wb_dtw + 262144;          // 2,097,152
  ushort_t* wb_f2  = wb_f1 + 2097152;          // 2,097,152
  ushort_t* wb_pw1 = wb_f2 + 2097152;          // 524,288 (k5 @0, k7 @262144)
  ushort_t* wb_pw2 = wb_pw1 + 524288;          // 524,288
  ushort_t* wb_proj= wb_pw2 + 524288;          // 786,432
  ushort_t* xnb    = wb_proj + 786432;         // 2,097,152 bf16
  float* g = (float*)(xnb + 2097152);          // 2,097,152 f32
  char* arena = (char*)(g + 2097152);
  // mamba/ffn phase
  ushort_t* xzb = (ushort_t*)arena;            // 8,388,608 ush (4096 x 2048)
  ushort_t* xcb = xzb + 8388608;               // 4,194,304 ush
  ushort_t* xcT = xcb + 4194304;               // 4,194,304 ush (1024 x 4096)
  ushort_t* dtT = xcT + 4194304;               // 4,194,304 ush (1024 x 4096)
  ushort_t* sT  = dtT + 4194304;               // 4,194,304 ush (1024 x 4096)
  ushort_t* yb  = sT + 4194304;                // 4,194,304 ush
  ushort_t* xdb_bf = yb + 4194304;             // 262,144 ush (4096 x 64)
  float* xdbp = (float*)(xdb_bf + 262144);     // 1,048,576 f32 (xproj partials)
  ushort_t* h1b = xcT;                         // 8,388,608 ush (FFN h1; xcT+dtT dead by FFN)
  // locals overlay (mamba scratch dead)
  ushort_t* xbf = (ushort_t*)arena;            // 2,097,152 ush
  float* lh  = (float*)(xbf + 2097152);        // 2,097,152 f32
  float* lhc = lh + 2097152;                   // 2,097,152 f32
  ushort_t* lhT = (ushort_t*)(lhc + 2097152);  // 2,097,152 ush
  ushort_t* cat = lhT + 2097152;               // 6,291,456 ush
  size_t need = (size_t)((char*)(xdbp + 1048576) - (char*)d_ws);
  if (ws_size < need) return;

  // ---------- fused weight conversions (bf16) ----------
  {
    CvtArgs ca;
    const float* srcs[NSEG] = {in_w, out_w, xp_w, ffn_w1, ffn_w2,
                               l5_pw1w, l7_pw1w, l5_pw2w, l7_pw2w, proj_w};
    ushort_t* dsts[NSEG] = {wb_in, wb_out, wb_xp, wb_f1, wb_f2,
                            wb_pw1, wb_pw1 + 262144, wb_pw2, wb_pw2 + 262144, wb_proj};
    int cnt4[NSEG] = {4194304 / 4, 2097152 / 4, 262144 / 4, 2097152 / 4, 2097152 / 4,
                      262144 / 4, 262144 / 4, 262144 / 4, 262144 / 4, 786432 / 4};
    int acc = 0;
    for (int s = 0; s < NSEG; ++s) { ca.src[s] = srcs[s]; ca.dst[s] = dsts[s]; ca.start4[s] = acc; acc += cnt4[s]; }
    cvt_all_kernel<<<2048, 256, 0, stream>>>(ca, acc);
  }
  cvtpad_dtw_kernel<<<1024, 256, 0, stream>>>(dt_w, wb_dtw);

  hipMemcpyAsync(g, x, N_BLD * 4, hipMemcpyDeviceToDevice, stream);

  const long sBL = (long)LL * DD;  // 524288
  for (int i = 0; i < 2; ++i) {
    ln_kernel<<<1024, 256, 0, stream>>>(g, ln_w + i * 512, ln_b + i * 512, xnb);
    for (int dir = 0; dir < 2; ++dir) {
      int m = 2 * i + dir;
      const ushort_t* wi = wb_in + (long)m * 1048576;
      const float* bi = in_b + (long)m * 2048;
      // in-proj: 4096 x 2048 x 512 -> xzb (bf16)
      if (dir == 0)
        mgemm<128, 0, 1, 0, 0, 0, 1, 0><<<dim3(16, 32, 1), 256, 0, stream>>>(
            xnb, wi, bi, xzb, 512, 512, 512, 2048, 2048, 0, 0, 0, 1.f);
      else
        mgemm<128, 0, 1, 0, 1, 0, 1, 0><<<dim3(16, 32, 1), 256, 0, stream>>>(
            xnb, wi, bi, xzb, 512, 512, 512, 2048, 2048, 0, 0, 0, 1.f);
      mconv_kernel<<<16384, 256, 0, stream>>>(xzb, conv_w + (long)m * 4096,
                                              conv_b + (long)m * 1024, xcb);
      transpose_bf_kernel<<<dim3(32, 32, 4), dim3(32, 8), 0, stream>>>(xcb, xcT);
      // xproj: 4096 x 64 x 1024, split-K x4 -> f32 partials, reduce -> bf16 xdb
      mgemm<64, 0, 0, 0, 0, 0, 0, 1><<<dim3(1, 32, 4), 256, 0, stream>>>(
          xcb, wb_xp + (long)m * 65536, nullptr, xdbp, 256, 1024, 1024, 64, 64,
          0, 0, 262144, 1.f);
      reduce4bf_kernel<<<256, 256, 0, stream>>>(xdbp, xdb_bf);
      // dt-proj (transposed): dtT(1024 x 4096) = softplus(dtw_pad x xdb_bf^T + dt_b)
      mgemm<128, 3, 2, 0, 0, 0, 1, 0><<<dim3(32, 8, 1), 256, 0, stream>>>(
          wb_dtw + (long)m * 65536, xdb_bf, dt_b + (long)m * 1024, dtT,
          64, 64, 64, 4096, 4096, 0, 0, 0, 1.f);
      // fused scan (pass1 + wave butterfly + pass2)
      fscan_kernel<<<1024, 256, 0, stream>>>(dtT, xcT, xdb_bf,
                                             A_log + (long)m * 16384, sT);
      // gate + untranspose -> yb (b,l,d)
      gate_kernel<<<dim3(32, 32, 4), dim3(32, 8), 0, stream>>>(
          sT, xcb, xzb, Dp + (long)m * 1024, yb);
      // out-proj: 4096 x 512 x 1024, g += 0.5*(...)
      if (dir == 0)
        mgemm<64, 0, 1, 1, 0, 0, 0, 0><<<dim3(8, 32, 1), 256, 0, stream>>>(
            yb, wb_out + (long)m * 524288, out_b + (long)m * 512, g, 1024, 1024, 1024, 512,
            512, 0, 0, 0, 0.5f);
      else
        mgemm<64, 0, 1, 1, 0, 1, 0, 0><<<dim3(8, 32, 1), 256, 0, stream>>>(
            yb, wb_out + (long)m * 524288, out_b + (long)m * 512, g, 1024, 1024, 1024, 512,
            512, 0, 0, 0, 0.5f);
    }
    // FFN
    ln_kernel<<<1024, 256, 0, stream>>>(g, ffn_ln_w + i * 512, ffn_ln_b + i * 512, xnb);
    mgemm<128, 2, 1, 0, 0, 0, 1, 0><<<dim3(16, 32, 1), 256, 0, stream>>>(
        xnb, wb_f1 + (long)i * 1048576, ffn_b1 + (long)i * 2048, h1b, 512, 512, 512, 2048,
        2048, 0, 0, 0, 1.f);
    mgemm<64, 0, 1, 1, 0, 0, 0, 0><<<dim3(8, 32, 1), 256, 0, stream>>>(
        h1b, wb_f2 + (long)i * 1048576, ffn_b2 + (long)i * 512, g, 2048, 2048, 2048, 512,
        512, 0, 0, 0, 1.f);
  }

  // ---------- locals ----------
  cvt_kernel<<<512, 256, 0, stream>>>(x, xbf, N_BLD);
  for (int k = 0; k < 2; ++k) {
    const ushort_t* pw1w = wb_pw1 + (long)k * 262144;
    const float* pw1b = k ? l7_pw1b : l5_pw1b;
    const float* dww  = k ? l7_dww  : l5_dww;
    const ushort_t* pw2w = wb_pw2 + (long)k * 262144;
    const float* pw2b = k ? l7_pw2b : l5_pw2b;
    // pw1: per batch  lh[b](D,L) = W(512x512) x xbf[b](1024x512)^T
    mgemm<64, 0, 2, 0, 0, 0, 0, 0><<<dim3(16, 4, 4), 256, 0, stream>>>(
        pw1w, xbf, pw1b, lh, 512, 512, 512, 1024, 1024, 0, sBL, sBL, 1.f);
    inorm_silu_kernel<<<2048, 256, 0, stream>>>(lh);
    if (k)
      dwconv_kernel<7><<<8192, 256, 0, stream>>>(lh, dww, lhc);
    else
      dwconv_kernel<5><<<8192, 256, 0, stream>>>(lh, dww, lhc);
    inorm_silu_kernel<<<2048, 256, 0, stream>>>(lhc);
    transpose_dl_kernel<<<dim3(32, 16, 4), dim3(32, 8), 0, stream>>>(lhc, lhT);
    // pw2: per batch  cat[b](1024, cols 512k..512k+512) = lhT[b](1024x512) x W^T -> bf16
    mgemm<64, 0, 1, 0, 0, 0, 1, 0><<<dim3(8, 8, 4), 256, 0, stream>>>(
        lhT, pw2w, pw2b, cat + (k ? 1024 : 512), 512, 512, 512, 1536, 512,
        sBL, 0, (long)LL * 1536, 1.f);
  }
  copyg_kernel<<<8192, 256, 0, stream>>>(g, cat);
  hipMemcpyAsync(outp, x, N_BLD * 4, hipMemcpyDeviceToDevice, stream);
  // out += cat(4096x1536) @ proj_w^T (512x1536)
  mgemm<64, 0, 1, 1, 0, 0, 0, 0><<<dim3(8, 32, 1), 256, 0, stream>>>(
      cat, wb_proj, proj_b, outp, 1536, 1536, 1536, 512, 512, 0, 0, 0, 1.f);
}